// Round 6
// baseline (1539.733 us; speedup 1.0000x reference)
//
#include <hip/hip_runtime.h>
#include <hip/hip_bf16.h>

// TreeLSTM on MI355X. B=256 trees, 256 leaves (depth 9), H=512, X=300, 5 classes.
// f32 I/O; bf16 MFMA compute; f32 cell state. Output f32 [256,511,5].
//
// R6: VGPR staging (compiler software-pipelines global loads across the barrier)
// + fragment-ordered conflict-free LDS layout + fused logits epilogue
// (atomicAdd over 8 col-blocks, out pre-init to lin_b) + padded bf16 emb.

typedef __bf16 bf16;
typedef bf16  bf16x8 __attribute__((ext_vector_type(8)));
typedef float f32x4  __attribute__((ext_vector_type(4)));

__device__ __forceinline__ float sigm(float x){ return 1.0f/(1.0f + __expf(-x)); }
__device__ __forceinline__ float tanh_f(float x){ return 1.0f - 2.0f/(__expf(2.0f*x)+1.0f); }

// ---- weight/emb converts ----
__global__ void cvt_pad_w(const float* __restrict__ src, bf16* __restrict__ dst){
  const int row = blockIdx.x, c = threadIdx.x;   // 1536 x 320
  dst[row*320 + c] = (bf16)(c < 300 ? src[row*300 + c] : 0.f);
}
__global__ void cvt_emb(const float* __restrict__ src, bf16* __restrict__ dst){
  const int row = blockIdx.x, c = threadIdx.x;   // 32000 x 320
  dst[row*320 + c] = (bf16)(c < 300 ? src[(size_t)row*300 + c] : 0.f);
}
__global__ void cvt(const float* __restrict__ src, bf16* __restrict__ dst, int n){
  const int i = blockIdx.x*256 + threadIdx.x;
  if (i < n) dst[i] = (bf16)src[i];
}
__global__ void out_init(float* __restrict__ out, const float* __restrict__ linb, int n){
  const int i = blockIdx.x*256 + threadIdx.x;
  if (i < n) out[i] = linb[i - (i/5)*5];
}

// Fragment-ordered LDS: 64x32 bf16 tile = 4 KB = 256 slots x 16B.
// Thread t stages slot t (ds_write_b128 at t*16B — contiguous, conflict-free).
// Slot t holds (row = (t>>6)*16 + (t&15), k-octet = (t>>4)&3) of the tile.
// A-read: lane l, row-tile rt -> lds[tile + rt*512 + l*8]. B-read: wave w -> w*512 + l*8.

// ---- leaf: x=embp[wordid]; iou = x @ W_iou^T + b; cell; fused logits ----
__global__ __launch_bounds__(256)
void leaf_kernel(const int* __restrict__ wordid, const bf16* __restrict__ embp,
                 const bf16* __restrict__ Wpad, const float* __restrict__ Wb,
                 bf16* __restrict__ hcur, float* __restrict__ ccur,
                 const float* __restrict__ linw, float* __restrict__ out)
{
  __shared__ bf16 lds[12288];   // 4 staging tiles (16 KB); epilogue h-tile reuses (17.2 KB)
  const int t = threadIdx.x;
  const int mrow0 = blockIdx.x*64, nblk = blockIdx.y*64;
  const int l = t&63, w = t>>6, lane16 = t&15, quad = (t>>4)&3;

  const int srow = (t>>6)*16 + (t&15);
  const int skq  = (t>>4)&3;
  const int wid  = wordid[mrow0 + srow];
  const bf16* gA  = embp + (size_t)wid*320 + skq*8;
  const bf16* gB0 = Wpad + (size_t)(       nblk + srow)*320 + skq*8;
  const bf16* gB1 = Wpad + (size_t)(512  + nblk + srow)*320 + skq*8;
  const bf16* gB2 = Wpad + (size_t)(1024 + nblk + srow)*320 + skq*8;

  f32x4 acc[3][4];
  const f32x4 zero = {0.f,0.f,0.f,0.f};
  #pragma unroll
  for(int o=0;o<3;o++){
    #pragma unroll
    for(int rt=0;rt<4;rt++) acc[o][rt]=zero;
  }

  for (int ks=0; ks<10; ks++){
    bf16x8 vA  = *(const bf16x8*)gA;
    bf16x8 vB0 = *(const bf16x8*)gB0;
    bf16x8 vB1 = *(const bf16x8*)gB1;
    bf16x8 vB2 = *(const bf16x8*)gB2;
    gA += 32; gB0 += 32; gB1 += 32; gB2 += 32;
    *(bf16x8*)&lds[        t*8] = vA;
    *(bf16x8*)&lds[2048 +  t*8] = vB0;
    *(bf16x8*)&lds[4096 +  t*8] = vB1;
    *(bf16x8*)&lds[6144 +  t*8] = vB2;
    __syncthreads();
    bf16x8 bfrag[3];
    #pragma unroll
    for(int g=0;g<3;g++) bfrag[g] = *(const bf16x8*)&lds[2048 + g*2048 + w*512 + l*8];
    #pragma unroll
    for(int rt=0;rt<4;rt++){
      bf16x8 a = *(const bf16x8*)&lds[rt*512 + l*8];
      #pragma unroll
      for(int g=0;g<3;g++)
        acc[g][rt] = __builtin_amdgcn_mfma_f32_16x16x32_bf16(a, bfrag[g], acc[g][rt], 0,0,0);
    }
    __syncthreads();
  }

  float* lh = (float*)lds;                       // 64 x 67 f32 h-tile (17.2 KB <= 24 KB)
  const int j = nblk + w*16 + lane16;
  const float bi=Wb[j], bo=Wb[512+j], bu=Wb[1024+j];
  #pragma unroll
  for(int rt=0;rt<4;rt++){
    #pragma unroll
    for(int reg=0;reg<4;reg++){
      const int lrow = rt*16 + quad*4 + reg;     // C/D: row=quad*4+reg, col=lane16
      const int row  = mrow0 + lrow;
      float iv=acc[0][rt][reg]+bi, ov=acc[1][rt][reg]+bo, uv=acc[2][rt][reg]+bu;
      float c = sigm(iv)*tanh_f(uv);
      float h = sigm(ov)*tanh_f(c);
      ccur[(size_t)row*512 + j] = c;
      hcur[(size_t)row*512 + j] = (bf16)h;
      lh[lrow*67 + (w*16+lane16)] = h;
    }
  }
  __syncthreads();
  {
    const int lrow = t>>2, seg = t&3;            // 4 threads/row, 16 cols each
    const float* hp = &lh[lrow*67 + seg*16];
    float s[5];
    #pragma unroll
    for(int c=0;c<5;c++){
      const float* wp = linw + c*512 + nblk + seg*16;
      float a = 0.f;
      #pragma unroll
      for(int i=0;i<16;i++) a += hp[i]*wp[i];
      s[c]=a;
    }
    #pragma unroll
    for(int c=0;c<5;c++){ s[c]+=__shfl_xor(s[c],1,64); s[c]+=__shfl_xor(s[c],2,64); }
    if (seg==0){
      const int row = mrow0 + lrow;
      const int node = (row>>8)*511 + (row&255);
      #pragma unroll
      for(int c=0;c<5;c++) atomicAdd(&out[(size_t)node*5+c], s[c]);
    }
  }
}

// ---- level: h_cat @ {U_iou,U_f}^T, full cell with c_f; fused logits ----
__global__ __launch_bounds__(256)
void level_kernel(const bf16* __restrict__ hprev, bf16* __restrict__ hcur,
                  const float* __restrict__ cprev, float* __restrict__ ccur,
                  const bf16* __restrict__ Ubf, const float* __restrict__ Uioub,
                  const bf16* __restrict__ Ufbf, const float* __restrict__ Ufb,
                  const float* __restrict__ linw, float* __restrict__ out,
                  int lgm, int mask, int off)
{
  __shared__ bf16 lds[12288];   // A + 5 gates, 4 KB each = 24 KB
  const int t = threadIdx.x;
  const int mrow0 = blockIdx.x*64, nblk = blockIdx.y*64;
  const int l = t&63, w = t>>6, lane16 = t&15, quad = (t>>4)&3;

  const int srow = (t>>6)*16 + (t&15);
  const int skq  = (t>>4)&3;
  const bf16* gA  = hprev + (size_t)(mrow0 + srow)*1024 + skq*8;   // h_cat rows contiguous
  const bf16* gB0 = Ubf  + (size_t)(       nblk + srow)*1024 + skq*8;
  const bf16* gB1 = Ubf  + (size_t)(512  + nblk + srow)*1024 + skq*8;
  const bf16* gB2 = Ubf  + (size_t)(1024 + nblk + srow)*1024 + skq*8;
  const bf16* gB3 = Ufbf + (size_t)(       nblk + srow)*1024 + skq*8;
  const bf16* gB4 = Ufbf + (size_t)(512  + nblk + srow)*1024 + skq*8;

  f32x4 acc[5][4];
  const f32x4 zero = {0.f,0.f,0.f,0.f};
  #pragma unroll
  for(int o=0;o<5;o++){
    #pragma unroll
    for(int rt=0;rt<4;rt++) acc[o][rt]=zero;
  }

  for (int ks=0; ks<32; ks++){
    bf16x8 vA  = *(const bf16x8*)gA;
    bf16x8 vB0 = *(const bf16x8*)gB0;
    bf16x8 vB1 = *(const bf16x8*)gB1;
    bf16x8 vB2 = *(const bf16x8*)gB2;
    bf16x8 vB3 = *(const bf16x8*)gB3;
    bf16x8 vB4 = *(const bf16x8*)gB4;
    gA += 32; gB0 += 32; gB1 += 32; gB2 += 32; gB3 += 32; gB4 += 32;
    *(bf16x8*)&lds[         t*8] = vA;
    *(bf16x8*)&lds[ 2048 +  t*8] = vB0;
    *(bf16x8*)&lds[ 4096 +  t*8] = vB1;
    *(bf16x8*)&lds[ 6144 +  t*8] = vB2;
    *(bf16x8*)&lds[ 8192 +  t*8] = vB3;
    *(bf16x8*)&lds[10240 +  t*8] = vB4;
    __syncthreads();
    bf16x8 bfrag[5];
    #pragma unroll
    for(int g=0;g<5;g++) bfrag[g] = *(const bf16x8*)&lds[2048 + g*2048 + w*512 + l*8];
    #pragma unroll
    for(int rt=0;rt<4;rt++){
      bf16x8 a = *(const bf16x8*)&lds[rt*512 + l*8];
      #pragma unroll
      for(int g=0;g<5;g++)
        acc[g][rt] = __builtin_amdgcn_mfma_f32_16x16x32_bf16(a, bfrag[g], acc[g][rt], 0,0,0);
    }
    __syncthreads();
  }

  float* lh = (float*)lds;
  const int j = nblk + w*16 + lane16;
  const float bi =Uioub[j], bo=Uioub[512+j], bu=Uioub[1024+j];
  const float bfl=Ufb[j],   bfr=Ufb[512+j];
  #pragma unroll
  for(int rt=0;rt<4;rt++){
    #pragma unroll
    for(int reg=0;reg<4;reg++){
      const int lrow = rt*16 + quad*4 + reg;
      const int row  = mrow0 + lrow;
      float iv=acc[0][rt][reg]+bi, ov=acc[1][rt][reg]+bo, uv=acc[2][rt][reg]+bu;
      float fl=acc[3][rt][reg]+bfl, fr=acc[4][rt][reg]+bfr;
      float cl = cprev[((size_t)row*2  )*512 + j];
      float cr = cprev[((size_t)row*2+1)*512 + j];
      float cf = sigm(fl)*cl + sigm(fr)*cr;
      float c  = sigm(iv)*tanh_f(uv) + cf;
      float h  = sigm(ov)*tanh_f(c);
      ccur[(size_t)row*512 + j] = c;
      hcur[(size_t)row*512 + j] = (bf16)h;
      lh[lrow*67 + (w*16+lane16)] = h;
    }
  }
  __syncthreads();
  {
    const int lrow = t>>2, seg = t&3;
    const float* hp = &lh[lrow*67 + seg*16];
    float s[5];
    #pragma unroll
    for(int c=0;c<5;c++){
      const float* wp = linw + c*512 + nblk + seg*16;
      float a = 0.f;
      #pragma unroll
      for(int i=0;i<16;i++) a += hp[i]*wp[i];
      s[c]=a;
    }
    #pragma unroll
    for(int c=0;c<5;c++){ s[c]+=__shfl_xor(s[c],1,64); s[c]+=__shfl_xor(s[c],2,64); }
    if (seg==0){
      const int row = mrow0 + lrow;
      const int node = (row>>lgm)*511 + off + (row&mask);
      #pragma unroll
      for(int c=0;c<5;c++) atomicAdd(&out[(size_t)node*5+c], s[c]);
    }
  }
}

__global__ void zero_out(float* out, int n){
  int i = blockIdx.x*256 + threadIdx.x;
  if (i < n) out[i] = 0.f;
}

extern "C" void kernel_launch(void* const* d_in, const int* in_sizes, int n_in,
                              void* d_out, int out_size, void* d_ws, size_t ws_size,
                              hipStream_t stream)
{
  const int*   wordid = (const int*)d_in[0];
  const float* emb    = (const float*)d_in[1];
  const float* Wiou   = (const float*)d_in[2];
  const float* Wioub  = (const float*)d_in[3];
  const float* Uiou   = (const float*)d_in[4];
  const float* Uioub  = (const float*)d_in[5];
  const float* Uf     = (const float*)d_in[6];
  const float* Ufb    = (const float*)d_in[7];
  const float* linw   = (const float*)d_in[8];
  const float* linb   = (const float*)d_in[9];
  float* out = (float*)d_out;

  const size_t WPD = (size_t)1536*320*2;
  const size_t UIO = (size_t)1536*1024*2;
  const size_t UFB = (size_t)1024*1024*2;
  const size_t EMBP = (size_t)32000*320*2;        // 20.48 MB padded bf16 emb
  const size_t WAREA = WPD + UIO + UFB;

  int nc = 0; size_t R = 0; bool alias = false;
  for (int tt = 1; tt <= 4; tt <<= 1){
    const size_t Rr = (size_t)65536 / tt;
    const bool al = (tt == 1) && (Rr*1024 >= EMBP);
    const size_t need = WAREA + Rr*4608 + (al ? 0 : EMBP);
    if (ws_size >= need){ nc = tt; R = Rr; alias = al; break; }
  }
  if (nc == 0){
    zero_out<<<(out_size+255)/256, 256, 0, stream>>>(out, out_size);
    return;
  }

  char* ws = (char*)d_ws;
  bf16* Wpad = (bf16*)ws;
  bf16* Ubf  = (bf16*)(ws + WPD);
  bf16* Ufbf = (bf16*)(ws + WPD + UIO);
  bf16*  hA  = (bf16*)(ws + WAREA);
  bf16*  hB  = (bf16*)(ws + WAREA + R*1024);
  float* cA  = (float*)(ws + WAREA + R*1536);
  float* cB  = (float*)(ws + WAREA + R*3584);
  bf16* embp = alias ? (bf16*)cB : (bf16*)(ws + WAREA + R*4608);

  cvt_pad_w<<<1536, 320, 0, stream>>>(Wiou, Wpad);
  cvt<<<(1536*1024+255)/256, 256, 0, stream>>>(Uiou, Ubf, 1536*1024);
  cvt<<<(1024*1024+255)/256, 256, 0, stream>>>(Uf, Ufbf, 1024*1024);
  cvt_emb<<<32000, 320, 0, stream>>>(emb, embp);
  out_init<<<(out_size+255)/256, 256, 0, stream>>>(out, linb, out_size);

  const int Bc = 256 / nc;
  const int offs[9] = {0,256,384,448,480,496,504,508,510};
  for (int ch = 0; ch < nc; ch++){
    const int* wid = wordid + (size_t)ch*R;
    float*     och = out + (size_t)ch*Bc*511*5;
    leaf_kernel<<<dim3((int)(R/64), 8), 256, 0, stream>>>(wid, embp, Wpad, Wioub,
                                                          hA, cA, linw, och);
    for (int lv=1; lv<=8; lv++){
      const int m = 256>>lv, lgm = 8-lv, rows = Bc*m;
      const bf16*  hin = (lv&1)? hA : hB;  bf16*  hout = (lv&1)? hB : hA;
      const float* cin = (lv&1)? cA : cB;  float* cout = (lv&1)? cB : cA;
      level_kernel<<<dim3(rows/64, 8), 256, 0, stream>>>(hin, hout, cin, cout,
                                                         Ubf, Uioub, Ufbf, Ufb,
                                                         linw, och, lgm, m-1, offs[lv]);
    }
  }
}

// Round 7
// 1038.373 us; speedup vs baseline: 1.4828x; 1.4828x over previous
//
#include <hip/hip_runtime.h>
#include <hip/hip_bf16.h>

// TreeLSTM on MI355X. B=256 trees, 256 leaves (depth 9), H=512, X=300, 5 classes.
// f32 I/O; bf16 MFMA compute; f32 cell state. Output f32 [256,511,5].
//
// R7: memory plan fits in ~178 MB (leaf+level-1 chunked 4x into reusable scratch;
// levels 2-8 ping-pong full-size regions). Kernel bodies = R4's proven inner loop
// (stride-40 LDS, VGPR staging, indexed loads). Unfused logits kernels.

typedef __bf16 bf16;
typedef bf16  bf16x8 __attribute__((ext_vector_type(8)));
typedef float f32x4  __attribute__((ext_vector_type(4)));

__device__ __forceinline__ float sigm(float x){ return 1.0f/(1.0f + __expf(-x)); }
__device__ __forceinline__ float tanh_f(float x){ return 1.0f - 2.0f/(__expf(2.0f*x)+1.0f); }

// ---- converts ----
__global__ void cvt_pad_w(const float* __restrict__ src, bf16* __restrict__ dst){
  const int row = blockIdx.x, c = threadIdx.x;   // 1536 x 320
  dst[row*320 + c] = (bf16)(c < 300 ? src[row*300 + c] : 0.f);
}
__global__ void cvt_emb(const float* __restrict__ src, bf16* __restrict__ dst){
  const int row = blockIdx.x, c = threadIdx.x;   // 32000 x 320
  dst[row*320 + c] = (bf16)(c < 300 ? src[(size_t)row*300 + c] : 0.f);
}
__global__ void cvt(const float* __restrict__ src, bf16* __restrict__ dst, int n){
  const int i = blockIdx.x*256 + threadIdx.x;
  if (i < n) dst[i] = (bf16)src[i];
}

// ---- leaf: x=embp[wordid]; iou = x @ W_iou^T + b; cell ---- (R4 body, branch-free A)
__global__ __launch_bounds__(256)
void leaf_kernel(const int* __restrict__ wordid, const bf16* __restrict__ embp,
                 const bf16* __restrict__ Wpad, const float* __restrict__ Wb,
                 bf16* __restrict__ hcur, float* __restrict__ ccur)
{
  __shared__ bf16 lsA[64*40];      // stride 40 elems (80 B) — proven R4 layout
  __shared__ bf16 lsB[3][64*40];
  const int t = threadIdx.x;
  const int mrow0 = blockIdx.x*64, nblk = blockIdx.y*64;
  const int r = t>>2, kc = (t&3)*8;
  const int lane16 = t&15, quad = (t&63)>>4, w = t>>6;

  f32x4 acc[3][4];
  const f32x4 zero = {0.f,0.f,0.f,0.f};
  #pragma unroll
  for(int o=0;o<3;o++){
    #pragma unroll
    for(int rt=0;rt<4;rt++) acc[o][rt]=zero;
  }

  const int wid = wordid[mrow0 + r];
  const bf16* arow = embp + (size_t)wid*320;
  const int col = nblk + r;
  for (int k0=0;k0<320;k0+=32){
    *(bf16x8*)&lsA[r*40+kc]    = *(const bf16x8*)&arow[k0+kc];
    *(bf16x8*)&lsB[0][r*40+kc] = *(const bf16x8*)&Wpad[(size_t)col*320        + k0+kc];
    *(bf16x8*)&lsB[1][r*40+kc] = *(const bf16x8*)&Wpad[(size_t)(512+col)*320  + k0+kc];
    *(bf16x8*)&lsB[2][r*40+kc] = *(const bf16x8*)&Wpad[(size_t)(1024+col)*320 + k0+kc];
    __syncthreads();
    bf16x8 bfrag[3];
    #pragma unroll
    for(int o=0;o<3;o++) bfrag[o] = *(const bf16x8*)&lsB[o][(w*16+lane16)*40 + quad*8];
    #pragma unroll
    for(int rt=0;rt<4;rt++){
      bf16x8 a = *(const bf16x8*)&lsA[(rt*16+lane16)*40 + quad*8];
      #pragma unroll
      for(int o=0;o<3;o++)
        acc[o][rt] = __builtin_amdgcn_mfma_f32_16x16x32_bf16(a, bfrag[o], acc[o][rt], 0,0,0);
    }
    __syncthreads();
  }
  const int j = nblk + w*16 + lane16;
  const float bi=Wb[j], bo=Wb[512+j], bu=Wb[1024+j];
  #pragma unroll
  for(int rt=0;rt<4;rt++){
    #pragma unroll
    for(int reg=0;reg<4;reg++){
      const int row = mrow0 + rt*16 + quad*4 + reg;   // C/D: row=quad*4+reg, col=lane16
      float iv=acc[0][rt][reg]+bi, ov=acc[1][rt][reg]+bo, uv=acc[2][rt][reg]+bu;
      float c = sigm(iv)*tanh_f(uv);
      float h = sigm(ov)*tanh_f(c);
      ccur[(size_t)row*512 + j] = c;
      hcur[(size_t)row*512 + j] = (bf16)h;
    }
  }
}

// ---- level: h_cat @ {U_iou,U_f}^T, full cell with c_f ---- (R4 body)
__global__ __launch_bounds__(256)
void level_kernel(const bf16* __restrict__ hprev, bf16* __restrict__ hcur,
                  const float* __restrict__ cprev, float* __restrict__ ccur,
                  const bf16* __restrict__ Ubf, const float* __restrict__ Uioub,
                  const bf16* __restrict__ Ufbf, const float* __restrict__ Ufb)
{
  __shared__ bf16 lsA[64*40];
  __shared__ bf16 lsB[5][64*40];
  const int t = threadIdx.x;
  const int mrow0 = blockIdx.x*64, nblk = blockIdx.y*64;
  const int r = t>>2, kc = (t&3)*8;
  const int lane16 = t&15, quad = (t&63)>>4, w = t>>6;

  f32x4 acc[5][4];
  const f32x4 zero = {0.f,0.f,0.f,0.f};
  #pragma unroll
  for(int o=0;o<5;o++){
    #pragma unroll
    for(int rt=0;rt<4;rt++) acc[o][rt]=zero;
  }

  const bf16* arow = hprev + (size_t)(mrow0 + r)*1024;   // children rows 2p,2p+1 contiguous
  const int col = nblk + r;
  for (int k0=0;k0<1024;k0+=32){
    *(bf16x8*)&lsA[r*40+kc]    = *(const bf16x8*)&arow[k0+kc];
    *(bf16x8*)&lsB[0][r*40+kc] = *(const bf16x8*)&Ubf[(size_t)col*1024        + k0+kc];
    *(bf16x8*)&lsB[1][r*40+kc] = *(const bf16x8*)&Ubf[(size_t)(512+col)*1024  + k0+kc];
    *(bf16x8*)&lsB[2][r*40+kc] = *(const bf16x8*)&Ubf[(size_t)(1024+col)*1024 + k0+kc];
    *(bf16x8*)&lsB[3][r*40+kc] = *(const bf16x8*)&Ufbf[(size_t)col*1024       + k0+kc];
    *(bf16x8*)&lsB[4][r*40+kc] = *(const bf16x8*)&Ufbf[(size_t)(512+col)*1024 + k0+kc];
    __syncthreads();
    bf16x8 bfrag[5];
    #pragma unroll
    for(int o=0;o<5;o++) bfrag[o] = *(const bf16x8*)&lsB[o][(w*16+lane16)*40 + quad*8];
    #pragma unroll
    for(int rt=0;rt<4;rt++){
      bf16x8 a = *(const bf16x8*)&lsA[(rt*16+lane16)*40 + quad*8];
      #pragma unroll
      for(int o=0;o<5;o++)
        acc[o][rt] = __builtin_amdgcn_mfma_f32_16x16x32_bf16(a, bfrag[o], acc[o][rt], 0,0,0);
    }
    __syncthreads();
  }
  const int j = nblk + w*16 + lane16;
  const float bi =Uioub[j], bo=Uioub[512+j], bu=Uioub[1024+j];
  const float bfl=Ufb[j],   bfr=Ufb[512+j];
  #pragma unroll
  for(int rt=0;rt<4;rt++){
    #pragma unroll
    for(int reg=0;reg<4;reg++){
      const int row = mrow0 + rt*16 + quad*4 + reg;
      float iv=acc[0][rt][reg]+bi, ov=acc[1][rt][reg]+bo, uv=acc[2][rt][reg]+bu;
      float fl=acc[3][rt][reg]+bfl, fr=acc[4][rt][reg]+bfr;
      float cl = cprev[((size_t)row*2  )*512 + j];
      float cr = cprev[((size_t)row*2+1)*512 + j];
      float cf = sigm(fl)*cl + sigm(fr)*cr;
      float c  = sigm(iv)*tanh_f(uv) + cf;
      float h  = sigm(ov)*tanh_f(c);
      ccur[(size_t)row*512 + j] = c;
      hcur[(size_t)row*512 + j] = (bf16)h;
    }
  }
}

// ---- logits: out[node*5+c] = h_row . lin_w[c] + lin_b[c]; node from global row ----
__global__ __launch_bounds__(256)
void logits_kernel(const bf16* __restrict__ h, const float* __restrict__ linw,
                   const float* __restrict__ linb, float* __restrict__ out,
                   int rowbase, int lgm, int mask, int off){
  const int row = blockIdx.x*4 + (threadIdx.x>>6);
  const int l = threadIdx.x & 63;
  bf16x8 hv = *(const bf16x8*)(h + (size_t)row*512 + l*8);
  float hf[8];
  #pragma unroll
  for(int jj=0;jj<8;jj++) hf[jj] = (float)hv[jj];
  float s[5];
  #pragma unroll
  for(int c=0;c<5;c++){
    const f32x4 w0 = *(const f32x4*)(linw + c*512 + l*8);
    const f32x4 w1 = *(const f32x4*)(linw + c*512 + l*8 + 4);
    float a = 0.f;
    #pragma unroll
    for(int jj=0;jj<4;jj++) a += hf[jj]*w0[jj] + hf[4+jj]*w1[jj];
    s[c]=a;
  }
  #pragma unroll
  for(int o=32;o>0;o>>=1){
    #pragma unroll
    for(int c=0;c<5;c++) s[c] += __shfl_down(s[c], o, 64);
  }
  if (l==0){
    const int g = rowbase + row;
    const int node = (g>>lgm)*511 + off + (g&mask);
    #pragma unroll
    for(int c=0;c<5;c++) out[(size_t)node*5+c] = s[c] + linb[c];
  }
}

__global__ void zero_out(float* out, int n){
  int i = blockIdx.x*256 + threadIdx.x;
  if (i < n) out[i] = 0.f;
}

extern "C" void kernel_launch(void* const* d_in, const int* in_sizes, int n_in,
                              void* d_out, int out_size, void* d_ws, size_t ws_size,
                              hipStream_t stream)
{
  const int*   wordid = (const int*)d_in[0];
  const float* emb    = (const float*)d_in[1];
  const float* Wiou   = (const float*)d_in[2];
  const float* Wioub  = (const float*)d_in[3];
  const float* Uiou   = (const float*)d_in[4];
  const float* Uioub  = (const float*)d_in[5];
  const float* Uf     = (const float*)d_in[6];
  const float* Ufb    = (const float*)d_in[7];
  const float* linw   = (const float*)d_in[8];
  const float* linb   = (const float*)d_in[9];
  float* out = (float*)d_out;

  // ---- fixed-region layout ----
  const size_t oWPD  = 0;
  const size_t oUBF  = oWPD + (size_t)1536*320*2;            //   983,040
  const size_t oUFB  = oUBF + (size_t)1536*1024*2;           // 4,128,768
  const size_t oEMB  = oUFB + (size_t)1024*1024*2;           // 6,225,920
  const size_t oH1   = oEMB + (size_t)32000*320*2;           // 26,705,920
  const size_t oC1   = oH1  + (size_t)32768*512*2;           // 60,260,352
  const size_t oH0   = oC1  + (size_t)32768*512*4;           // 127,369,216
  // scratch h0/c0 sized by tier: R0 leaf rows per chunk
  size_t R0 = 0;
  {
    const size_t t4 = oH0 + (size_t)16384*512*(2+4);   // 177.7 MB
    const size_t t8 = oH0 + (size_t) 8192*512*(2+4);   // 152.5 MB
    if      (ws_size >= t4) R0 = 16384;
    else if (ws_size >= t8) R0 = 8192;
  }
  if (R0 == 0){
    zero_out<<<(out_size+255)/256, 256, 0, stream>>>(out, out_size);
    return;
  }

  char* ws = (char*)d_ws;
  bf16*  Wpad = (bf16*)(ws + oWPD);
  bf16*  Ubf  = (bf16*)(ws + oUBF);
  bf16*  Ufbf = (bf16*)(ws + oUFB);
  bf16*  embp = (bf16*)(ws + oEMB);
  bf16*  h1   = (bf16*)(ws + oH1);
  float* c1   = (float*)(ws + oC1);
  bf16*  h0   = (bf16*)(ws + oH0);
  float* c0   = (float*)(ws + oH0 + R0*1024);

  cvt_pad_w<<<1536, 320, 0, stream>>>(Wiou, Wpad);
  cvt<<<(1536*1024+255)/256, 256, 0, stream>>>(Uiou, Ubf, 1536*1024);
  cvt<<<(1024*1024+255)/256, 256, 0, stream>>>(Uf, Ufbf, 1024*1024);
  cvt_emb<<<32000, 320, 0, stream>>>(emb, embp);

  const int offs[9] = {0,256,384,448,480,496,504,508,510};
  const int nchunk = (int)(65536 / R0);

  // ---- leaf + level-1, chunked through h0/c0 scratch ----
  for (int ch = 0; ch < nchunk; ch++){
    const int* wid = wordid + (size_t)ch*R0;
    leaf_kernel<<<dim3((int)(R0/64), 8), 256, 0, stream>>>(wid, embp, Wpad, Wioub, h0, c0);
    logits_kernel<<<(int)(R0/4), 256, 0, stream>>>(h0, linw, linb, out,
                                                   (int)(ch*R0), 8, 255, 0);
    bf16*  h1c = h1 + (size_t)ch*(R0/2)*512;
    float* c1c = c1 + (size_t)ch*(R0/2)*512;
    level_kernel<<<dim3((int)(R0/128), 8), 256, 0, stream>>>(h0, h1c, c0, c1c,
                                                             Ubf, Uioub, Ufbf, Ufb);
  }
  logits_kernel<<<32768/4, 256, 0, stream>>>(h1, linw, linb, out, 0, 7, 127, offs[1]);

  // ---- levels 2..8: ping-pong h1/c1 <-> h0/c0 regions (sizes shrink) ----
  for (int lv = 2; lv <= 8; lv++){
    const int rows = 65536 >> lv;               // output rows this level
    const bf16*  hin  = (lv & 1) ? h0 : h1;
    bf16*        hout = (lv & 1) ? h1 : h0;
    const float* cin  = (lv & 1) ? c0 : c1;
    float*       cout = (lv & 1) ? c1 : c0;
    level_kernel<<<dim3(rows/64, 8), 256, 0, stream>>>(hin, hout, cin, cout,
                                                       Ubf, Uioub, Ufbf, Ufb);
    logits_kernel<<<rows/4, 256, 0, stream>>>(hout, linw, linb, out,
                                              0, 8-lv, (256>>lv)-1, offs[lv]);
  }
}